// Round 8
// baseline (445.685 us; speedup 1.0000x reference)
//
#include <hip/hip_runtime.h>
#include <hip/hip_bf16.h>

constexpr int NB  = 8;
constexpr int TD  = 128;
constexpr int HID = 64;
constexpr int ROWS = 64;   // rows per block (halved: LDS ~19.7KB -> 8 blocks/CU)

typedef __attribute__((ext_vector_type(8))) short bf16x8;
typedef __attribute__((ext_vector_type(4))) float f32x4;

union U { unsigned u[4]; bf16x8 v; };

__device__ __forceinline__ unsigned int pk2(float a, float b) {
    __hip_bfloat162 h = __float22bfloat162_rn(float2{a, b});   // v_cvt_pk_bf16_f32 (RNE)
    unsigned int u; __builtin_memcpy(&u, &h, 4); return u;
}

// branch-free GELU: erf via Abramowitz-Stegun 7.1.26 (|err| < 1.5e-7)
__device__ __forceinline__ float gelu_fast(float x) {
    const float u = x * 0.70710678118f;
    const float a = fabsf(u);
    const float t = __builtin_amdgcn_rcpf(fmaf(0.3275911f, a, 1.0f));
    float p = fmaf(t, 1.061405429f, -1.453152027f);
    p = fmaf(t, p, 1.421413741f);
    p = fmaf(t, p, -0.284496736f);
    p = fmaf(t, p, 0.254829592f);
    p = p * t;
    const float e  = __builtin_amdgcn_exp2f(-a * a * 1.44269504f);
    const float pe = p * e;
    const float s  = (u >= 0.f) ? (2.0f - pe) : pe;   // 1 + erf(u)
    return 0.5f * x * s;
}

// ws layout (u32 pairs): [0,8192) mixW ; [8192,10240) W2 ; [10240,10496) W1 ; [10496,10752) W3
constexpr size_t WS_NEED_BYTES = 10752 * 4;

__global__ __launch_bounds__(256, 1)
void cvt_weights(const float* __restrict__ W1, const float* __restrict__ W2,
                 const float* __restrict__ W3, const float* __restrict__ mixW,
                 unsigned* __restrict__ ws)
{
    const int t = threadIdx.x;
#pragma unroll
    for (int i = 0; i < 32; ++i) {                 // mixW -> Wm[c][f], c=i*16+d, f=j*16+k
        const int p = t + i * 256;
        const int o = 2 * p;
        const int c = o >> 7, f = o & 127;
        const int ii = c >> 4, d = c & 15, j = f >> 4, k = f & 15;
        const float2 v = *(const float2*)(mixW + ii * 2048 + j * 256 + d * 16 + k);
        ws[p] = pk2(v.x, v.y);
    }
#pragma unroll
    for (int i = 0; i < 8; ++i) {                  // W2 row-major 64x64
        const int p = t + i * 256;
        const float2 v = *(const float2*)(W2 + 2 * p);
        ws[8192 + p] = pk2(v.x, v.y);
    }
    {
        const float2 v1 = *(const float2*)(W1 + 2 * t);   // W1 64x8
        ws[10240 + t] = pk2(v1.x, v1.y);
        const float2 v3 = *(const float2*)(W3 + 2 * t);   // W3 8x64
        ws[10496 + t] = pk2(v3.x, v3.y);
    }
}

template<bool USE_WS>
__global__ __launch_bounds__(256, 8)
void soft_equiv(const float* __restrict__ z,  const float* __restrict__ W1,
                const float* __restrict__ b1, const float* __restrict__ W2,
                const float* __restrict__ b2, const float* __restrict__ W3,
                const float* __restrict__ mixW, const float* __restrict__ gb,
                const unsigned short* __restrict__ wsu,
                float* __restrict__ out)
{
    __shared__ __align__(16) unsigned short zs[ROWS * TD];   // 16 KB bf16 z, swizzled
    __shared__ __align__(16) unsigned short hn[ROWS * NB];   // 1 KB bf16 norms
    __shared__ float sca[ROWS * 9];                           // 2.3 KB (1+softplus)

    const int t    = threadIdx.x;
    const int lane = t & 63;
    const int w    = t >> 6;        // wave id 0..3
    const int hi   = lane >> 4;     // 0..3
    const int lo   = lane & 15;
    const size_t row0 = (size_t)blockIdx.x * ROWS;
    const float* ztile = z + row0 * TD;
    const f32x4 z4 = {0.f, 0.f, 0.f, 0.f};

    // ====== phase 1: stage z -> bf16 swizzled LDS; in-register fp32 norms =======
#pragma unroll
    for (int i = 0; i < 2; ++i) {
        const int idx = t + i * 256;               // (row, bundle)
        const int r = idx >> 3, b = idx & 7;
        const float* p = ztile + r * TD + b * 16;
        const float4 v0 = *(const float4*)(p);
        const float4 v1 = *(const float4*)(p + 4);
        const float4 v2 = *(const float4*)(p + 8);
        const float4 v3 = *(const float4*)(p + 12);
        const int sw = r & 7;
        uint4 q0 = { pk2(v0.x, v0.y), pk2(v0.z, v0.w), pk2(v1.x, v1.y), pk2(v1.z, v1.w) };
        uint4 q1 = { pk2(v2.x, v2.y), pk2(v2.z, v2.w), pk2(v3.x, v3.y), pk2(v3.z, v3.w) };
        *(uint4*)&zs[r * TD + (((2 * b    ) ^ sw) * 8)] = q0;
        *(uint4*)&zs[r * TD + (((2 * b + 1) ^ sw) * 8)] = q1;
        float s0 = 0.f, s1 = 0.f, s2 = 0.f, s3 = 0.f;
        s0 = fmaf(v0.x, v0.x, s0); s1 = fmaf(v0.y, v0.y, s1);
        s2 = fmaf(v0.z, v0.z, s2); s3 = fmaf(v0.w, v0.w, s3);
        s0 = fmaf(v1.x, v1.x, s0); s1 = fmaf(v1.y, v1.y, s1);
        s2 = fmaf(v1.z, v1.z, s2); s3 = fmaf(v1.w, v1.w, s3);
        s0 = fmaf(v2.x, v2.x, s0); s1 = fmaf(v2.y, v2.y, s1);
        s2 = fmaf(v2.z, v2.z, s2); s3 = fmaf(v2.w, v2.w, s3);
        s0 = fmaf(v3.x, v3.x, s0); s1 = fmaf(v3.y, v3.y, s1);
        s2 = fmaf(v3.z, v3.z, s2); s3 = fmaf(v3.w, v3.w, s3);
        const float nr = sqrtf((s0 + s1) + (s2 + s3)) + 1e-8f;
        __hip_bfloat16 hb = __float2bfloat16(nr);
        unsigned short us; __builtin_memcpy(&us, &hb, 2);
        hn[r * NB + b] = us;
    }

    // ====== MLP weight fragments ======
    bf16x8 a1f[4];
    bf16x8 a2f[4][2];
    bf16x8 a3f[2];
    if constexpr (USE_WS) {
#pragma unroll
        for (int mt = 0; mt < 4; ++mt) {
            U c = {};
            if (hi == 0) c.v = *(const bf16x8*)(wsu + 2 * 10240 + (mt * 16 + lo) * 8);
            a1f[mt] = c.v;
        }
#pragma unroll
        for (int mt = 0; mt < 4; ++mt)
#pragma unroll
            for (int kk = 0; kk < 2; ++kk)
                a2f[mt][kk] = *(const bf16x8*)(wsu + 2 * 8192 + (mt * 16 + lo) * HID + kk * 32 + hi * 8);
#pragma unroll
        for (int kk = 0; kk < 2; ++kk) {
            U c = {};
            if (lo < NB) c.v = *(const bf16x8*)(wsu + 2 * 10496 + lo * HID + kk * 32 + hi * 8);
            a3f[kk] = c.v;
        }
    } else {
#pragma unroll
        for (int mt = 0; mt < 4; ++mt) {
            U c = {};
            if (hi == 0) {
                const float4 x = *(const float4*)(W1 + (mt * 16 + lo) * NB);
                const float4 y = *(const float4*)(W1 + (mt * 16 + lo) * NB + 4);
                c.u[0] = pk2(x.x, x.y); c.u[1] = pk2(x.z, x.w);
                c.u[2] = pk2(y.x, y.y); c.u[3] = pk2(y.z, y.w);
            }
            a1f[mt] = c.v;
        }
#pragma unroll
        for (int mt = 0; mt < 4; ++mt)
#pragma unroll
            for (int kk = 0; kk < 2; ++kk) {
                const float* p = W2 + (mt * 16 + lo) * HID + kk * 32 + hi * 8;
                const float4 x = *(const float4*)p;
                const float4 y = *(const float4*)(p + 4);
                U c;
                c.u[0] = pk2(x.x, x.y); c.u[1] = pk2(x.z, x.w);
                c.u[2] = pk2(y.x, y.y); c.u[3] = pk2(y.z, y.w);
                a2f[mt][kk] = c.v;
            }
#pragma unroll
        for (int kk = 0; kk < 2; ++kk) {
            U c = {};
            if (lo < NB) {
                const float* p = W3 + lo * HID + kk * 32 + hi * 8;
                const float4 x = *(const float4*)p;
                const float4 y = *(const float4*)(p + 4);
                c.u[0] = pk2(x.x, x.y); c.u[1] = pk2(x.z, x.w);
                c.u[2] = pk2(y.x, y.y); c.u[3] = pk2(y.z, y.w);
            }
            a3f[kk] = c.v;
        }
    }
    float4 b1v[4], b2v[4];
#pragma unroll
    for (int mt = 0; mt < 4; ++mt) {
        b1v[mt] = ((const float4*)b1)[mt * 4 + hi];
        b2v[mt] = ((const float4*)b2)[mt * 4 + hi];
    }

    __syncthreads();

    // ====== phase 2: MLP on MFMA (wave w owns rows 16w..16w+15) ======
    bf16x8 b1f;
    {
        U c = {};
        if (hi == 0)
            c.v = *(const bf16x8*)&hn[(16 * w + lo) * NB];
        b1f = c.v;
    }

    const int slA = lo + 32 * (hi & 1);
    const int slB = slA + 16;
    const bool selhi = (hi & 2) != 0;

    unsigned pkh[4][2];
#pragma unroll
    for (int mt = 0; mt < 4; ++mt) {
        f32x4 c = __builtin_amdgcn_mfma_f32_16x16x32_bf16(a1f[mt], b1f, z4, 0, 0, 0);
        const float4 bb = b1v[mt];
        const float g0 = gelu_fast(c[0] + bb.x);
        const float g1 = gelu_fast(c[1] + bb.y);
        const float g2 = gelu_fast(c[2] + bb.z);
        const float g3 = gelu_fast(c[3] + bb.w);
        pkh[mt][0] = pk2(g0, g1);
        pkh[mt][1] = pk2(g2, g3);
    }

    bf16x8 b2f[2];
#pragma unroll
    for (int kk = 0; kk < 2; ++kk) {
        U c;
        const unsigned a0 = __shfl((int)pkh[2*kk  ][0], slA, 64);
        const unsigned a1 = __shfl((int)pkh[2*kk  ][1], slA, 64);
        const unsigned a2 = __shfl((int)pkh[2*kk  ][0], slB, 64);
        const unsigned a3 = __shfl((int)pkh[2*kk  ][1], slB, 64);
        const unsigned d0 = __shfl((int)pkh[2*kk+1][0], slA, 64);
        const unsigned d1 = __shfl((int)pkh[2*kk+1][1], slA, 64);
        const unsigned d2 = __shfl((int)pkh[2*kk+1][0], slB, 64);
        const unsigned d3 = __shfl((int)pkh[2*kk+1][1], slB, 64);
        c.u[0] = selhi ? d0 : a0; c.u[1] = selhi ? d1 : a1;
        c.u[2] = selhi ? d2 : a2; c.u[3] = selhi ? d3 : a3;
        b2f[kk] = c.v;
    }

    unsigned pkh2[4][2];
#pragma unroll
    for (int mt = 0; mt < 4; ++mt) {
        f32x4 c = __builtin_amdgcn_mfma_f32_16x16x32_bf16(a2f[mt][0], b2f[0], z4, 0, 0, 0);
        c = __builtin_amdgcn_mfma_f32_16x16x32_bf16(a2f[mt][1], b2f[1], c, 0, 0, 0);
        const float4 bb = b2v[mt];
        const float g0 = gelu_fast(c[0] + bb.x);
        const float g1 = gelu_fast(c[1] + bb.y);
        const float g2 = gelu_fast(c[2] + bb.z);
        const float g3 = gelu_fast(c[3] + bb.w);
        pkh2[mt][0] = pk2(g0, g1);
        pkh2[mt][1] = pk2(g2, g3);
    }

    {
        U c0, c1;
#pragma unroll
        for (int kk = 0; kk < 2; ++kk) {
            const unsigned a0 = __shfl((int)pkh2[2*kk  ][0], slA, 64);
            const unsigned a1 = __shfl((int)pkh2[2*kk  ][1], slA, 64);
            const unsigned a2 = __shfl((int)pkh2[2*kk  ][0], slB, 64);
            const unsigned a3 = __shfl((int)pkh2[2*kk  ][1], slB, 64);
            const unsigned d0 = __shfl((int)pkh2[2*kk+1][0], slA, 64);
            const unsigned d1 = __shfl((int)pkh2[2*kk+1][1], slA, 64);
            const unsigned d2 = __shfl((int)pkh2[2*kk+1][0], slB, 64);
            const unsigned d3 = __shfl((int)pkh2[2*kk+1][1], slB, 64);
            if (kk == 0) {
                c0.u[0] = selhi ? d0 : a0; c0.u[1] = selhi ? d1 : a1;
                c0.u[2] = selhi ? d2 : a2; c0.u[3] = selhi ? d3 : a3;
            } else {
                c1.u[0] = selhi ? d0 : a0; c1.u[1] = selhi ? d1 : a1;
                c1.u[2] = selhi ? d2 : a2; c1.u[3] = selhi ? d3 : a3;
            }
        }
        f32x4 s3 = __builtin_amdgcn_mfma_f32_16x16x32_bf16(a3f[0], c0.v, z4, 0, 0, 0);
        s3 = __builtin_amdgcn_mfma_f32_16x16x32_bf16(a3f[1], c1.v, s3, 0, 0, 0);
        if (hi < 2) {
            const int r = 16 * w + lo;
#pragma unroll
            for (int e = 0; e < 4; ++e) {
                const float x  = s3[e];
                const float sp = fmaxf(x, 0.f) +
                    0.69314718f * __builtin_amdgcn_logf(
                        1.0f + __builtin_amdgcn_exp2f(-fabsf(x) * 1.44269504f));
                sca[r * 9 + hi * 4 + e] = 1.0f + sp;
            }
        }
    }

    // ====== mixed-einsum B fragments ======
    bf16x8 bfr[2][4];
#pragma unroll
    for (int n = 0; n < 2; ++n) {
        const int col = w * 32 + n * 16 + lo;
#pragma unroll
        for (int kk = 0; kk < 4; ++kk) {
            if constexpr (USE_WS) {
                bfr[n][kk] = *(const bf16x8*)(wsu + col * TD + kk * 32 + hi * 8);
            } else {
                const int k0 = kk * 32 + hi * 8;
                const float* p = mixW + (col >> 4) * 2048 + (k0 >> 4) * 256
                                      + (col & 15) * 16 + (k0 & 15);
                const float4 x = *(const float4*)p;
                const float4 y = *(const float4*)(p + 4);
                U c;
                c.u[0] = pk2(x.x, x.y); c.u[1] = pk2(x.z, x.w);
                c.u[2] = pk2(y.x, y.y); c.u[3] = pk2(y.z, y.w);
                bfr[n][kk] = c.v;
            }
        }
    }
    const float g0 = 1.f / (1.f + __builtin_amdgcn_exp2f(-gb[2 * w + 0] * 1.44269504f));
    const float g1 = 1.f / (1.f + __builtin_amdgcn_exp2f(-gb[2 * w + 1] * 1.44269504f));

    __syncthreads();   // sca complete

    // ====== phase 3: mixed einsum MFMA + fused epilogue ======
#pragma unroll
    for (int m = 0; m < 4; ++m) {
        const int ar = m * 16 + lo;
        bf16x8 af[4];
#pragma unroll
        for (int kk = 0; kk < 4; ++kk) {
            const int slot = (kk * 4 + hi) ^ (ar & 7);
            af[kk] = *(const bf16x8*)&zs[ar * TD + slot * 8];
        }
#pragma unroll
        for (int n = 0; n < 2; ++n) {
            f32x4 acc = z4;
#pragma unroll
            for (int kk = 0; kk < 4; ++kk)
                acc = __builtin_amdgcn_mfma_f32_16x16x32_bf16(af[kk], bfr[n][kk], acc, 0, 0, 0);
            const int col = w * 32 + n * 16 + lo;
            const float gg = n ? g1 : g0;
            const int sl = col >> 3, cw = col & 7;
#pragma unroll
            for (int e = 0; e < 4; ++e) {
                const int rr = m * 16 + hi * 4 + e;
                const float zv = __uint_as_float(
                    (unsigned int)zs[rr * TD + ((sl ^ (rr & 7)) * 8) + cw] << 16);
                const float sc = sca[rr * 9 + 2 * w + n];
                out[(row0 + rr) * TD + col] = fmaf(zv, sc, gg * acc[e]);
            }
        }
    }
}

extern "C" void kernel_launch(void* const* d_in, const int* in_sizes, int n_in,
                              void* d_out, int out_size, void* d_ws, size_t ws_size,
                              hipStream_t stream) {
    const float* z    = (const float*)d_in[0];
    const float* W1   = (const float*)d_in[1];
    const float* b1   = (const float*)d_in[2];
    const float* W2   = (const float*)d_in[3];
    const float* b2   = (const float*)d_in[4];
    const float* W3   = (const float*)d_in[5];
    const float* mixW = (const float*)d_in[6];
    const float* gb   = (const float*)d_in[7];
    float* out = (float*)d_out;

    const int B = in_sizes[0] / TD;
    if (ws_size >= WS_NEED_BYTES && d_ws != nullptr) {
        cvt_weights<<<1, 256, 0, stream>>>(W1, W2, W3, mixW, (unsigned*)d_ws);
        soft_equiv<true><<<B / ROWS, 256, 0, stream>>>(
            z, W1, b1, W2, b2, W3, mixW, gb, (const unsigned short*)d_ws, out);
    } else {
        soft_equiv<false><<<B / ROWS, 256, 0, stream>>>(
            z, W1, b1, W2, b2, W3, mixW, gb, nullptr, out);
    }
}

// Round 11
// 394.111 us; speedup vs baseline: 1.1309x; 1.1309x over previous
//
#include <hip/hip_runtime.h>
#include <hip/hip_bf16.h>

constexpr int NB  = 8;
constexpr int TD  = 128;
constexpr int HID = 64;
constexpr int ROWS = 64;   // rows per tile
constexpr int NT   = 4;    // tiles per block (persistent pipeline)

typedef __attribute__((ext_vector_type(8))) short bf16x8;
typedef __attribute__((ext_vector_type(4))) float f32x4;

union U { unsigned u[4]; bf16x8 v; };

__device__ __forceinline__ unsigned int pk2(float a, float b) {
    __hip_bfloat162 h = __float22bfloat162_rn(float2{a, b});   // v_cvt_pk_bf16_f32 (RNE)
    unsigned int u; __builtin_memcpy(&u, &h, 4); return u;
}

// branch-free GELU: erf via Abramowitz-Stegun 7.1.26 (|err| < 1.5e-7)
__device__ __forceinline__ float gelu_fast(float x) {
    const float u = x * 0.70710678118f;
    const float a = fabsf(u);
    const float t = __builtin_amdgcn_rcpf(fmaf(0.3275911f, a, 1.0f));
    float p = fmaf(t, 1.061405429f, -1.453152027f);
    p = fmaf(t, p, 1.421413741f);
    p = fmaf(t, p, -0.284496736f);
    p = fmaf(t, p, 0.254829592f);
    p = p * t;
    const float e  = __builtin_amdgcn_exp2f(-a * a * 1.44269504f);
    const float pe = p * e;
    const float s  = (u >= 0.f) ? (2.0f - pe) : pe;   // 1 + erf(u)
    return 0.5f * x * s;
}

// ws layout (u32 pairs): [0,8192) mixW ; [8192,10240) W2 ; [10240,10496) W1 ; [10496,10752) W3
constexpr size_t WS_NEED_BYTES = 10752 * 4;

__global__ __launch_bounds__(256, 1)
void cvt_weights(const float* __restrict__ W1, const float* __restrict__ W2,
                 const float* __restrict__ W3, const float* __restrict__ mixW,
                 unsigned* __restrict__ ws)
{
    const int t = threadIdx.x;
#pragma unroll
    for (int i = 0; i < 32; ++i) {                 // mixW -> Wm[c][f], c=i*16+d, f=j*16+k
        const int p = t + i * 256;
        const int o = 2 * p;
        const int c = o >> 7, f = o & 127;
        const int ii = c >> 4, d = c & 15, j = f >> 4, k = f & 15;
        const float2 v = *(const float2*)(mixW + ii * 2048 + j * 256 + d * 16 + k);
        ws[p] = pk2(v.x, v.y);
    }
#pragma unroll
    for (int i = 0; i < 8; ++i) {                  // W2 row-major 64x64
        const int p = t + i * 256;
        const float2 v = *(const float2*)(W2 + 2 * p);
        ws[8192 + p] = pk2(v.x, v.y);
    }
    {
        const float2 v1 = *(const float2*)(W1 + 2 * t);   // W1 64x8
        ws[10240 + t] = pk2(v1.x, v1.y);
        const float2 v3 = *(const float2*)(W3 + 2 * t);   // W3 8x64
        ws[10496 + t] = pk2(v3.x, v3.y);
    }
}

template<bool USE_WS>
__global__ __launch_bounds__(256, 4)
void soft_equiv(const float* __restrict__ z,  const float* __restrict__ W1,
                const float* __restrict__ b1, const float* __restrict__ W2,
                const float* __restrict__ b2, const float* __restrict__ W3,
                const float* __restrict__ mixW, const float* __restrict__ gb,
                const unsigned short* __restrict__ wsu,
                float* __restrict__ out)
{
    __shared__ __align__(16) unsigned short zs[2][ROWS * TD];  // 2 x 16 KB, dbuf
    __shared__ __align__(16) unsigned short hn[ROWS * NB];     // 1 KB
    __shared__ float sca[ROWS * 9];                            // 2.3 KB

    const int t    = threadIdx.x;
    const int lane = t & 63;
    const int w    = t >> 6;        // wave id 0..3
    const int hi   = lane >> 4;     // 0..3
    const int lo   = lane & 15;
    const size_t tile0 = (size_t)blockIdx.x * NT;
    const f32x4 z4 = {0.f, 0.f, 0.f, 0.f};

    // ---- block-resident: mixed-einsum B fragments + gates ----
    bf16x8 bfr[2][4];
#pragma unroll
    for (int n = 0; n < 2; ++n) {
        const int col = w * 32 + n * 16 + lo;
#pragma unroll
        for (int kk = 0; kk < 4; ++kk) {
            if constexpr (USE_WS) {
                bfr[n][kk] = *(const bf16x8*)(wsu + col * TD + kk * 32 + hi * 8);
            } else {
                const int k0 = kk * 32 + hi * 8;
                const float* p = mixW + (col >> 4) * 2048 + (k0 >> 4) * 256
                                      + (col & 15) * 16 + (k0 & 15);
                const float4 x = *(const float4*)p;
                const float4 y = *(const float4*)(p + 4);
                U c;
                c.u[0] = pk2(x.x, x.y); c.u[1] = pk2(x.z, x.w);
                c.u[2] = pk2(y.x, y.y); c.u[3] = pk2(y.z, y.w);
                bfr[n][kk] = c.v;
            }
        }
    }
    const float g0 = 1.f / (1.f + __builtin_amdgcn_exp2f(-gb[2 * w + 0] * 1.44269504f));
    const float g1 = 1.f / (1.f + __builtin_amdgcn_exp2f(-gb[2 * w + 1] * 1.44269504f));

    // ---- prologue: stage tile 0 -> zs[0], hn ----
    {
        const float* zt = z + tile0 * ROWS * TD;
#pragma unroll
        for (int i = 0; i < 2; ++i) {
            const int idx = t + i * 256;           // (row, bundle)
            const int r = idx >> 3, b = idx & 7;
            const float* p = zt + r * TD + b * 16;
            const float4 v0 = *(const float4*)(p);
            const float4 v1 = *(const float4*)(p + 4);
            const float4 v2 = *(const float4*)(p + 8);
            const float4 v3 = *(const float4*)(p + 12);
            const int sw = r & 7;
            uint4 q0 = { pk2(v0.x, v0.y), pk2(v0.z, v0.w), pk2(v1.x, v1.y), pk2(v1.z, v1.w) };
            uint4 q1 = { pk2(v2.x, v2.y), pk2(v2.z, v2.w), pk2(v3.x, v3.y), pk2(v3.z, v3.w) };
            *(uint4*)&zs[0][r * TD + (((2 * b    ) ^ sw) * 8)] = q0;
            *(uint4*)&zs[0][r * TD + (((2 * b + 1) ^ sw) * 8)] = q1;
            float s0 = 0.f, s1 = 0.f, s2 = 0.f, s3 = 0.f;
            s0 = fmaf(v0.x, v0.x, s0); s1 = fmaf(v0.y, v0.y, s1);
            s2 = fmaf(v0.z, v0.z, s2); s3 = fmaf(v0.w, v0.w, s3);
            s0 = fmaf(v1.x, v1.x, s0); s1 = fmaf(v1.y, v1.y, s1);
            s2 = fmaf(v1.z, v1.z, s2); s3 = fmaf(v1.w, v1.w, s3);
            s0 = fmaf(v2.x, v2.x, s0); s1 = fmaf(v2.y, v2.y, s1);
            s2 = fmaf(v2.z, v2.z, s2); s3 = fmaf(v2.w, v2.w, s3);
            s0 = fmaf(v3.x, v3.x, s0); s1 = fmaf(v3.y, v3.y, s1);
            s2 = fmaf(v3.z, v3.z, s2); s3 = fmaf(v3.w, v3.w, s3);
            const float nr = sqrtf((s0 + s1) + (s2 + s3)) + 1e-8f;
            __hip_bfloat16 hb = __float2bfloat16(nr);
            unsigned short us; __builtin_memcpy(&us, &hb, 2);
            hn[r * NB + b] = us;
        }
    }

    const int slA = lo + 32 * (hi & 1);   // shuffle sources for C->B handoff
    const int slB = slA + 16;
    const bool selhi = (hi & 2) != 0;

    int cur = 0;
#pragma unroll 1
    for (int it = 0; it < NT; ++it) {
        __syncthreads();                   // zs[cur], hn ready

        // ---- MLP fragments: reloaded per tile via opaque base (defeats LICM) ----
        bf16x8 a1f[4], a2f[4][2], a3f[2];
        float4 b1v[4], b2v[4];
        if constexpr (USE_WS) {
            unsigned long long wka = (unsigned long long)(const void*)wsu;
            asm volatile("" : "+s"(wka));
            const unsigned short* wk = (const unsigned short*)wka;
#pragma unroll
            for (int mt = 0; mt < 4; ++mt) {
                U c = {};
                if (hi == 0) c.v = *(const bf16x8*)(wk + 2 * 10240 + (mt * 16 + lo) * 8);
                a1f[mt] = c.v;
            }
#pragma unroll
            for (int mt = 0; mt < 4; ++mt)
#pragma unroll
                for (int kk = 0; kk < 2; ++kk)
                    a2f[mt][kk] = *(const bf16x8*)(wk + 2 * 8192 + (mt * 16 + lo) * HID + kk * 32 + hi * 8);
#pragma unroll
            for (int kk = 0; kk < 2; ++kk) {
                U c = {};
                if (lo < NB) c.v = *(const bf16x8*)(wk + 2 * 10496 + lo * HID + kk * 32 + hi * 8);
                a3f[kk] = c.v;
            }
        } else {
#pragma unroll
            for (int mt = 0; mt < 4; ++mt) {
                U c = {};
                if (hi == 0) {
                    const float4 x = *(const float4*)(W1 + (mt * 16 + lo) * NB);
                    const float4 y = *(const float4*)(W1 + (mt * 16 + lo) * NB + 4);
                    c.u[0] = pk2(x.x, x.y); c.u[1] = pk2(x.z, x.w);
                    c.u[2] = pk2(y.x, y.y); c.u[3] = pk2(y.z, y.w);
                }
                a1f[mt] = c.v;
            }
#pragma unroll
            for (int mt = 0; mt < 4; ++mt)
#pragma unroll
                for (int kk = 0; kk < 2; ++kk) {
                    const float* p = W2 + (mt * 16 + lo) * HID + kk * 32 + hi * 8;
                    const float4 x = *(const float4*)p;
                    const float4 y = *(const float4*)(p + 4);
                    U c;
                    c.u[0] = pk2(x.x, x.y); c.u[1] = pk2(x.z, x.w);
                    c.u[2] = pk2(y.x, y.y); c.u[3] = pk2(y.z, y.w);
                    a2f[mt][kk] = c.v;
                }
#pragma unroll
            for (int kk = 0; kk < 2; ++kk) {
                U c = {};
                if (lo < NB) {
                    const float* p = W3 + lo * HID + kk * 32 + hi * 8;
                    const float4 x = *(const float4*)p;
                    const float4 y = *(const float4*)(p + 4);
                    c.u[0] = pk2(x.x, x.y); c.u[1] = pk2(x.z, x.w);
                    c.u[2] = pk2(y.x, y.y); c.u[3] = pk2(y.z, y.w);
                }
                a3f[kk] = c.v;
            }
        }
        {
            unsigned long long b1a = (unsigned long long)(const void*)b1;
            unsigned long long b2a = (unsigned long long)(const void*)b2;
            asm volatile("" : "+s"(b1a), "+s"(b2a));
            const float4* pb1 = (const float4*)b1a;
            const float4* pb2 = (const float4*)b2a;
#pragma unroll
            for (int mt = 0; mt < 4; ++mt) {
                b1v[mt] = pb1[mt * 4 + hi];
                b2v[mt] = pb2[mt * 4 + hi];
            }
        }

        // ---- MLP on MFMA (wave w owns rows 16w..16w+15 of this tile) ----
        bf16x8 b1f;
        {
            U c = {};
            if (hi == 0) c.v = *(const bf16x8*)&hn[(16 * w + lo) * NB];
            b1f = c.v;
        }

        unsigned pkh[4][2];
#pragma unroll
        for (int mt = 0; mt < 4; ++mt) {
            f32x4 c = __builtin_amdgcn_mfma_f32_16x16x32_bf16(a1f[mt], b1f, z4, 0, 0, 0);
            const float4 bb = b1v[mt];
            const float ga = gelu_fast(c[0] + bb.x);
            const float gbv = gelu_fast(c[1] + bb.y);
            const float gc = gelu_fast(c[2] + bb.z);
            const float gd = gelu_fast(c[3] + bb.w);
            pkh[mt][0] = pk2(ga, gbv);
            pkh[mt][1] = pk2(gc, gd);
        }

        bf16x8 b2f[2];
#pragma unroll
        for (int kk = 0; kk < 2; ++kk) {
            U c;
            const unsigned a0 = __shfl((int)pkh[2*kk  ][0], slA, 64);
            const unsigned a1 = __shfl((int)pkh[2*kk  ][1], slA, 64);
            const unsigned a2 = __shfl((int)pkh[2*kk  ][0], slB, 64);
            const unsigned a3 = __shfl((int)pkh[2*kk  ][1], slB, 64);
            const unsigned d0 = __shfl((int)pkh[2*kk+1][0], slA, 64);
            const unsigned d1 = __shfl((int)pkh[2*kk+1][1], slA, 64);
            const unsigned d2 = __shfl((int)pkh[2*kk+1][0], slB, 64);
            const unsigned d3 = __shfl((int)pkh[2*kk+1][1], slB, 64);
            c.u[0] = selhi ? d0 : a0; c.u[1] = selhi ? d1 : a1;
            c.u[2] = selhi ? d2 : a2; c.u[3] = selhi ? d3 : a3;
            b2f[kk] = c.v;
        }

        unsigned pkh2[4][2];
#pragma unroll
        for (int mt = 0; mt < 4; ++mt) {
            f32x4 c = __builtin_amdgcn_mfma_f32_16x16x32_bf16(a2f[mt][0], b2f[0], z4, 0, 0, 0);
            c = __builtin_amdgcn_mfma_f32_16x16x32_bf16(a2f[mt][1], b2f[1], c, 0, 0, 0);
            const float4 bb = b2v[mt];
            const float ga = gelu_fast(c[0] + bb.x);
            const float gbv = gelu_fast(c[1] + bb.y);
            const float gc = gelu_fast(c[2] + bb.z);
            const float gd = gelu_fast(c[3] + bb.w);
            pkh2[mt][0] = pk2(ga, gbv);
            pkh2[mt][1] = pk2(gc, gd);
        }

        {
            U c0, c1;
#pragma unroll
            for (int kk = 0; kk < 2; ++kk) {
                const unsigned a0 = __shfl((int)pkh2[2*kk  ][0], slA, 64);
                const unsigned a1 = __shfl((int)pkh2[2*kk  ][1], slA, 64);
                const unsigned a2 = __shfl((int)pkh2[2*kk  ][0], slB, 64);
                const unsigned a3 = __shfl((int)pkh2[2*kk  ][1], slB, 64);
                const unsigned d0 = __shfl((int)pkh2[2*kk+1][0], slA, 64);
                const unsigned d1 = __shfl((int)pkh2[2*kk+1][1], slA, 64);
                const unsigned d2 = __shfl((int)pkh2[2*kk+1][0], slB, 64);
                const unsigned d3 = __shfl((int)pkh2[2*kk+1][1], slB, 64);
                if (kk == 0) {
                    c0.u[0] = selhi ? d0 : a0; c0.u[1] = selhi ? d1 : a1;
                    c0.u[2] = selhi ? d2 : a2; c0.u[3] = selhi ? d3 : a3;
                } else {
                    c1.u[0] = selhi ? d0 : a0; c1.u[1] = selhi ? d1 : a1;
                    c1.u[2] = selhi ? d2 : a2; c1.u[3] = selhi ? d3 : a3;
                }
            }
            f32x4 s3 = __builtin_amdgcn_mfma_f32_16x16x32_bf16(a3f[0], c0.v, z4, 0, 0, 0);
            s3 = __builtin_amdgcn_mfma_f32_16x16x32_bf16(a3f[1], c1.v, s3, 0, 0, 0);
            if (hi < 2) {
                const int r = 16 * w + lo;
#pragma unroll
                for (int e = 0; e < 4; ++e) {
                    const float x  = s3[e];
                    const float sp = fmaxf(x, 0.f) +
                        0.69314718f * __builtin_amdgcn_logf(
                            1.0f + __builtin_amdgcn_exp2f(-fabsf(x) * 1.44269504f));
                    sca[r * 9 + hi * 4 + e] = 1.0f + sp;
                }
            }
        }

        // ---- issue next tile's global loads (latency hides under mix phase) ----
        float4 sv0, sv1, sv2, sv3, sv4, sv5, sv6, sv7;
        int r0_, b0_, r1_, b1_;
        if (it < NT - 1) {
            const float* zt = z + (tile0 + it + 1) * ROWS * TD;
            {
                const int idx = t;
                r0_ = idx >> 3; b0_ = idx & 7;
                const float* p = zt + r0_ * TD + b0_ * 16;
                sv0 = *(const float4*)(p);
                sv1 = *(const float4*)(p + 4);
                sv2 = *(const float4*)(p + 8);
                sv3 = *(const float4*)(p + 12);
            }
            {
                const int idx = t + 256;
                r1_ = idx >> 3; b1_ = idx & 7;
                const float* p = zt + r1_ * TD + b1_ * 16;
                sv4 = *(const float4*)(p);
                sv5 = *(const float4*)(p + 4);
                sv6 = *(const float4*)(p + 8);
                sv7 = *(const float4*)(p + 12);
            }
        }

        __syncthreads();                   // sca ready

        // ---- mixed einsum MFMA + fused epilogue ----
        const unsigned short* zc = &zs[cur][0];
        const size_t row0 = (tile0 + it) * ROWS;
#pragma unroll
        for (int m = 0; m < 4; ++m) {
            const int ar = m * 16 + lo;
            bf16x8 af[4];
#pragma unroll
            for (int kk = 0; kk < 4; ++kk) {
                const int slot = (kk * 4 + hi) ^ (ar & 7);
                af[kk] = *(const bf16x8*)&zc[ar * TD + slot * 8];
            }
#pragma unroll
            for (int n = 0; n < 2; ++n) {
                f32x4 acc = z4;
#pragma unroll
                for (int kk = 0; kk < 4; ++kk)
                    acc = __builtin_amdgcn_mfma_f32_16x16x32_bf16(af[kk], bfr[n][kk], acc, 0, 0, 0);
                const int col = w * 32 + n * 16 + lo;
                const float gg = n ? g1 : g0;
                const int sl = col >> 3, cw = col & 7;
#pragma unroll
                for (int e = 0; e < 4; ++e) {
                    const int rr = m * 16 + hi * 4 + e;
                    const float zv = __uint_as_float(
                        (unsigned int)zc[rr * TD + ((sl ^ (rr & 7)) * 8) + cw] << 16);
                    const float sc = sca[rr * 9 + 2 * w + n];
                    out[(row0 + rr) * TD + col] = fmaf(zv, sc, gg * acc[e]);
                }
            }
        }

        // ---- convert + write next tile into zs[cur^1], hn ----
        if (it < NT - 1) {
            unsigned short* zn = &zs[cur ^ 1][0];
            {
                const int sw = r0_ & 7;
                uint4 q0 = { pk2(sv0.x, sv0.y), pk2(sv0.z, sv0.w), pk2(sv1.x, sv1.y), pk2(sv1.z, sv1.w) };
                uint4 q1 = { pk2(sv2.x, sv2.y), pk2(sv2.z, sv2.w), pk2(sv3.x, sv3.y), pk2(sv3.z, sv3.w) };
                *(uint4*)&zn[r0_ * TD + (((2 * b0_    ) ^ sw) * 8)] = q0;
                *(uint4*)&zn[r0_ * TD + (((2 * b0_ + 1) ^ sw) * 8)] = q1;
                float s0 = 0.f, s1 = 0.f, s2 = 0.f, s3 = 0.f;
                s0 = fmaf(sv0.x, sv0.x, s0); s1 = fmaf(sv0.y, sv0.y, s1);
                s2 = fmaf(sv0.z, sv0.z, s2); s3 = fmaf(sv0.w, sv0.w, s3);
                s0 = fmaf(sv1.x, sv1.x, s0); s1 = fmaf(sv1.y, sv1.y, s1);
                s2 = fmaf(sv1.z, sv1.z, s2); s3 = fmaf(sv1.w, sv1.w, s3);
                s0 = fmaf(sv2.x, sv2.x, s0); s1 = fmaf(sv2.y, sv2.y, s1);
                s2 = fmaf(sv2.z, sv2.z, s2); s3 = fmaf(sv2.w, sv2.w, s3);
                s0 = fmaf(sv3.x, sv3.x, s0); s1 = fmaf(sv3.y, sv3.y, s1);
                s2 = fmaf(sv3.z, sv3.z, s2); s3 = fmaf(sv3.w, sv3.w, s3);
                const float nr = sqrtf((s0 + s1) + (s2 + s3)) + 1e-8f;
                __hip_bfloat16 hb = __float2bfloat16(nr);
                unsigned short us; __builtin_memcpy(&us, &hb, 2);
                hn[r0_ * NB + b0_] = us;
            }
            {
                const int sw = r1_ & 7;
                uint4 q0 = { pk2(sv4.x, sv4.y), pk2(sv4.z, sv4.w), pk2(sv5.x, sv5.y), pk2(sv5.z, sv5.w) };
                uint4 q1 = { pk2(sv6.x, sv6.y), pk2(sv6.z, sv6.w), pk2(sv7.x, sv7.y), pk2(sv7.z, sv7.w) };
                *(uint4*)&zn[r1_ * TD + (((2 * b1_    ) ^ sw) * 8)] = q0;
                *(uint4*)&zn[r1_ * TD + (((2 * b1_ + 1) ^ sw) * 8)] = q1;
                float s0 = 0.f, s1 = 0.f, s2 = 0.f, s3 = 0.f;
                s0 = fmaf(sv4.x, sv4.x, s0); s1 = fmaf(sv4.y, sv4.y, s1);
                s2 = fmaf(sv4.z, sv4.z, s2); s3 = fmaf(sv4.w, sv4.w, s3);
                s0 = fmaf(sv5.x, sv5.x, s0); s1 = fmaf(sv5.y, sv5.y, s1);
                s2 = fmaf(sv5.z, sv5.z, s2); s3 = fmaf(sv5.w, sv5.w, s3);
                s0 = fmaf(sv6.x, sv6.x, s0); s1 = fmaf(sv6.y, sv6.y, s1);
                s2 = fmaf(sv6.z, sv6.z, s2); s3 = fmaf(sv6.w, sv6.w, s3);
                s0 = fmaf(sv7.x, sv7.x, s0); s1 = fmaf(sv7.y, sv7.y, s1);
                s2 = fmaf(sv7.z, sv7.z, s2); s3 = fmaf(sv7.w, sv7.w, s3);
                const float nr = sqrtf((s0 + s1) + (s2 + s3)) + 1e-8f;
                __hip_bfloat16 hb = __float2bfloat16(nr);
                unsigned short us; __builtin_memcpy(&us, &hb, 2);
                hn[r1_ * NB + b1_] = us;
            }
        }
        cur ^= 1;
    }
}

extern "C" void kernel_launch(void* const* d_in, const int* in_sizes, int n_in,
                              void* d_out, int out_size, void* d_ws, size_t ws_size,
                              hipStream_t stream) {
    const float* z    = (const float*)d_in[0];
    const float* W1   = (const float*)d_in[1];
    const float* b1   = (const float*)d_in[2];
    const float* W2   = (const float*)d_in[3];
    const float* b2   = (const float*)d_in[4];
    const float* W3   = (const float*)d_in[5];
    const float* mixW = (const float*)d_in[6];
    const float* gb   = (const float*)d_in[7];
    float* out = (float*)d_out;

    const int B = in_sizes[0] / TD;
    const int grid = B / (ROWS * NT);
    if (ws_size >= WS_NEED_BYTES && d_ws != nullptr) {
        cvt_weights<<<1, 256, 0, stream>>>(W1, W2, W3, mixW, (unsigned*)d_ws);
        soft_equiv<true><<<grid, 256, 0, stream>>>(
            z, W1, b1, W2, b2, W3, mixW, gb, (const unsigned short*)d_ws, out);
    } else {
        soft_equiv<false><<<grid, 256, 0, stream>>>(
            z, W1, b1, W2, b2, W3, mixW, gb, nullptr, out);
    }
}

// Round 15
// 113.604 us; speedup vs baseline: 3.9231x; 3.4692x over previous
//
#include <hip/hip_runtime.h>
#include <hip/hip_bf16.h>

constexpr int NB  = 8;
constexpr int TD  = 128;
constexpr int HID = 64;
constexpr int ROWS = 128;

typedef __attribute__((ext_vector_type(8))) short bf16x8;
typedef __attribute__((ext_vector_type(4))) float f32x4;

union U { unsigned u[4]; bf16x8 v; };

__device__ __forceinline__ unsigned int pk2(float a, float b) {
    __hip_bfloat162 h = __float22bfloat162_rn(float2{a, b});   // v_cvt_pk_bf16_f32 (RNE)
    unsigned int u; __builtin_memcpy(&u, &h, 4); return u;
}

// branch-free GELU: erf via Abramowitz-Stegun 7.1.26 (|err| < 1.5e-7)
__device__ __forceinline__ float gelu_fast(float x) {
    const float u = x * 0.70710678118f;
    const float a = fabsf(u);
    const float t = __builtin_amdgcn_rcpf(fmaf(0.3275911f, a, 1.0f));
    float p = fmaf(t, 1.061405429f, -1.453152027f);
    p = fmaf(t, p, 1.421413741f);
    p = fmaf(t, p, -0.284496736f);
    p = fmaf(t, p, 0.254829592f);
    p = p * t;
    const float e  = __builtin_amdgcn_exp2f(-a * a * 1.44269504f);
    const float pe = p * e;
    const float s  = (u >= 0.f) ? (2.0f - pe) : pe;   // 1 + erf(u)
    return 0.5f * x * s;
}

// ws layout (u32 pairs): [0,8192) mixW ; [8192,10240) W2 ; [10240,10496) W1 ; [10496,10752) W3
constexpr size_t WS_NEED_BYTES = 10752 * 4;

__global__ __launch_bounds__(256, 1)
void cvt_weights(const float* __restrict__ W1, const float* __restrict__ W2,
                 const float* __restrict__ W3, const float* __restrict__ mixW,
                 unsigned* __restrict__ ws)
{
    const int t = threadIdx.x;
#pragma unroll
    for (int i = 0; i < 32; ++i) {                 // mixW -> Wm[c][f], c=i*16+d, f=j*16+k
        const int p = t + i * 256;
        const int o = 2 * p;
        const int c = o >> 7, f = o & 127;
        const int ii = c >> 4, d = c & 15, j = f >> 4, k = f & 15;
        const float2 v = *(const float2*)(mixW + ii * 2048 + j * 256 + d * 16 + k);
        ws[p] = pk2(v.x, v.y);
    }
#pragma unroll
    for (int i = 0; i < 8; ++i) {                  // W2 row-major 64x64
        const int p = t + i * 256;
        const float2 v = *(const float2*)(W2 + 2 * p);
        ws[8192 + p] = pk2(v.x, v.y);
    }
    {
        const float2 v1 = *(const float2*)(W1 + 2 * t);   // W1 64x8
        ws[10240 + t] = pk2(v1.x, v1.y);
        const float2 v3 = *(const float2*)(W3 + 2 * t);   // W3 8x64
        ws[10496 + t] = pk2(v3.x, v3.y);
    }
}

template<bool USE_WS>
__global__ __launch_bounds__(256, 4)
void soft_equiv(const float* __restrict__ z,  const float* __restrict__ W1,
                const float* __restrict__ b1, const float* __restrict__ W2,
                const float* __restrict__ b2, const float* __restrict__ W3,
                const float* __restrict__ mixW, const float* __restrict__ gb,
                const unsigned short* __restrict__ wsu,
                float* __restrict__ out)
{
    __shared__ __align__(16) unsigned short zs[ROWS * TD];   // 32 KB bf16 z, swizzled
    __shared__ __align__(16) unsigned short hn[ROWS * NB];   // 2 KB bf16 norms
    __shared__ float sca[ROWS * 9];                           // 4.6 KB (1+softplus)

    const int t    = threadIdx.x;
    const int lane = t & 63;
    const int w    = t >> 6;        // wave id 0..3
    const int hi   = lane >> 4;     // 0..3
    const int lo   = lane & 15;
    const size_t row0 = (size_t)blockIdx.x * ROWS;
    const float* ztile = z + row0 * TD;
    const f32x4 z4 = {0.f, 0.f, 0.f, 0.f};

    // ====== phase 1: stage z -> bf16 swizzled LDS; in-register fp32 norms =======
#pragma unroll
    for (int i = 0; i < 4; ++i) {
        const int idx = t + i * 256;               // (row, bundle)
        const int r = idx >> 3, b = idx & 7;
        const float* p = ztile + r * TD + b * 16;
        const float4 v0 = *(const float4*)(p);
        const float4 v1 = *(const float4*)(p + 4);
        const float4 v2 = *(const float4*)(p + 8);
        const float4 v3 = *(const float4*)(p + 12);
        const int sw = r & 7;
        uint4 q0 = { pk2(v0.x, v0.y), pk2(v0.z, v0.w), pk2(v1.x, v1.y), pk2(v1.z, v1.w) };
        uint4 q1 = { pk2(v2.x, v2.y), pk2(v2.z, v2.w), pk2(v3.x, v3.y), pk2(v3.z, v3.w) };
        *(uint4*)&zs[r * TD + (((2 * b    ) ^ sw) * 8)] = q0;
        *(uint4*)&zs[r * TD + (((2 * b + 1) ^ sw) * 8)] = q1;
        float s0 = 0.f, s1 = 0.f, s2 = 0.f, s3 = 0.f;
        s0 = fmaf(v0.x, v0.x, s0); s1 = fmaf(v0.y, v0.y, s1);
        s2 = fmaf(v0.z, v0.z, s2); s3 = fmaf(v0.w, v0.w, s3);
        s0 = fmaf(v1.x, v1.x, s0); s1 = fmaf(v1.y, v1.y, s1);
        s2 = fmaf(v1.z, v1.z, s2); s3 = fmaf(v1.w, v1.w, s3);
        s0 = fmaf(v2.x, v2.x, s0); s1 = fmaf(v2.y, v2.y, s1);
        s2 = fmaf(v2.z, v2.z, s2); s3 = fmaf(v2.w, v2.w, s3);
        s0 = fmaf(v3.x, v3.x, s0); s1 = fmaf(v3.y, v3.y, s1);
        s2 = fmaf(v3.z, v3.z, s2); s3 = fmaf(v3.w, v3.w, s3);
        const float nr = sqrtf((s0 + s1) + (s2 + s3)) + 1e-8f;
        __hip_bfloat16 hb = __float2bfloat16(nr);
        unsigned short us; __builtin_memcpy(&us, &hb, 2);
        hn[r * NB + b] = us;
    }

    // ====== MLP weight fragments ======
    bf16x8 a1f[4];
    bf16x8 a2f[4][2];
    bf16x8 a3f[2];
    if constexpr (USE_WS) {
#pragma unroll
        for (int mt = 0; mt < 4; ++mt) {
            U c = {};
            if (hi == 0) c.v = *(const bf16x8*)(wsu + 2 * 10240 + (mt * 16 + lo) * 8);
            a1f[mt] = c.v;
        }
#pragma unroll
        for (int mt = 0; mt < 4; ++mt)
#pragma unroll
            for (int kk = 0; kk < 2; ++kk)
                a2f[mt][kk] = *(const bf16x8*)(wsu + 2 * 8192 + (mt * 16 + lo) * HID + kk * 32 + hi * 8);
#pragma unroll
        for (int kk = 0; kk < 2; ++kk) {
            U c = {};
            if (lo < NB) c.v = *(const bf16x8*)(wsu + 2 * 10496 + lo * HID + kk * 32 + hi * 8);
            a3f[kk] = c.v;
        }
    } else {
#pragma unroll
        for (int mt = 0; mt < 4; ++mt) {
            U c = {};
            if (hi == 0) {
                const float4 x = *(const float4*)(W1 + (mt * 16 + lo) * NB);
                const float4 y = *(const float4*)(W1 + (mt * 16 + lo) * NB + 4);
                c.u[0] = pk2(x.x, x.y); c.u[1] = pk2(x.z, x.w);
                c.u[2] = pk2(y.x, y.y); c.u[3] = pk2(y.z, y.w);
            }
            a1f[mt] = c.v;
        }
#pragma unroll
        for (int mt = 0; mt < 4; ++mt)
#pragma unroll
            for (int kk = 0; kk < 2; ++kk) {
                const float* p = W2 + (mt * 16 + lo) * HID + kk * 32 + hi * 8;
                const float4 x = *(const float4*)p;
                const float4 y = *(const float4*)(p + 4);
                U c;
                c.u[0] = pk2(x.x, x.y); c.u[1] = pk2(x.z, x.w);
                c.u[2] = pk2(y.x, y.y); c.u[3] = pk2(y.z, y.w);
                a2f[mt][kk] = c.v;
            }
#pragma unroll
        for (int kk = 0; kk < 2; ++kk) {
            U c = {};
            if (lo < NB) {
                const float* p = W3 + lo * HID + kk * 32 + hi * 8;
                const float4 x = *(const float4*)p;
                const float4 y = *(const float4*)(p + 4);
                c.u[0] = pk2(x.x, x.y); c.u[1] = pk2(x.z, x.w);
                c.u[2] = pk2(y.x, y.y); c.u[3] = pk2(y.z, y.w);
            }
            a3f[kk] = c.v;
        }
    }
    float4 b1v[4], b2v[4];
#pragma unroll
    for (int mt = 0; mt < 4; ++mt) {
        b1v[mt] = ((const float4*)b1)[mt * 4 + hi];
        b2v[mt] = ((const float4*)b2)[mt * 4 + hi];
    }

    __syncthreads();

    // ====== phase 2: MLP on MFMA (wave w owns rows 32w..32w+31) ======
    bf16x8 b1f[2];
#pragma unroll
    for (int nt = 0; nt < 2; ++nt) {
        U c = {};
        if (hi == 0)
            c.v = *(const bf16x8*)&hn[(32 * w + nt * 16 + lo) * NB];
        b1f[nt] = c.v;
    }

    const int slA = lo + 32 * (hi & 1);
    const int slB = slA + 16;
    const bool selhi = (hi & 2) != 0;

    unsigned pkh[2][4][2];
#pragma unroll
    for (int nt = 0; nt < 2; ++nt)
#pragma unroll
        for (int mt = 0; mt < 4; ++mt) {
            f32x4 c = __builtin_amdgcn_mfma_f32_16x16x32_bf16(a1f[mt], b1f[nt], z4, 0, 0, 0);
            const float4 bb = b1v[mt];
            const float g0 = gelu_fast(c[0] + bb.x);
            const float g1 = gelu_fast(c[1] + bb.y);
            const float g2 = gelu_fast(c[2] + bb.z);
            const float g3 = gelu_fast(c[3] + bb.w);
            pkh[nt][mt][0] = pk2(g0, g1);
            pkh[nt][mt][1] = pk2(g2, g3);
        }

    bf16x8 b2f[2][2];
#pragma unroll
    for (int nt = 0; nt < 2; ++nt)
#pragma unroll
        for (int kk = 0; kk < 2; ++kk) {
            U c;
            const unsigned a0 = __shfl((int)pkh[nt][2*kk  ][0], slA, 64);
            const unsigned a1 = __shfl((int)pkh[nt][2*kk  ][1], slA, 64);
            const unsigned a2 = __shfl((int)pkh[nt][2*kk  ][0], slB, 64);
            const unsigned a3 = __shfl((int)pkh[nt][2*kk  ][1], slB, 64);
            const unsigned d0 = __shfl((int)pkh[nt][2*kk+1][0], slA, 64);
            const unsigned d1 = __shfl((int)pkh[nt][2*kk+1][1], slA, 64);
            const unsigned d2 = __shfl((int)pkh[nt][2*kk+1][0], slB, 64);
            const unsigned d3 = __shfl((int)pkh[nt][2*kk+1][1], slB, 64);
            c.u[0] = selhi ? d0 : a0; c.u[1] = selhi ? d1 : a1;
            c.u[2] = selhi ? d2 : a2; c.u[3] = selhi ? d3 : a3;
            b2f[nt][kk] = c.v;
        }

    unsigned pkh2[2][4][2];
#pragma unroll
    for (int nt = 0; nt < 2; ++nt)
#pragma unroll
        for (int mt = 0; mt < 4; ++mt) {
            f32x4 c = __builtin_amdgcn_mfma_f32_16x16x32_bf16(a2f[mt][0], b2f[nt][0], z4, 0, 0, 0);
            c = __builtin_amdgcn_mfma_f32_16x16x32_bf16(a2f[mt][1], b2f[nt][1], c, 0, 0, 0);
            const float4 bb = b2v[mt];
            const float g0 = gelu_fast(c[0] + bb.x);
            const float g1 = gelu_fast(c[1] + bb.y);
            const float g2 = gelu_fast(c[2] + bb.z);
            const float g3 = gelu_fast(c[3] + bb.w);
            pkh2[nt][mt][0] = pk2(g0, g1);
            pkh2[nt][mt][1] = pk2(g2, g3);
        }

#pragma unroll
    for (int nt = 0; nt < 2; ++nt) {
        U c0, c1;
#pragma unroll
        for (int kk = 0; kk < 2; ++kk) {
            const unsigned a0 = __shfl((int)pkh2[nt][2*kk  ][0], slA, 64);
            const unsigned a1 = __shfl((int)pkh2[nt][2*kk  ][1], slA, 64);
            const unsigned a2 = __shfl((int)pkh2[nt][2*kk  ][0], slB, 64);
            const unsigned a3 = __shfl((int)pkh2[nt][2*kk  ][1], slB, 64);
            const unsigned d0 = __shfl((int)pkh2[nt][2*kk+1][0], slA, 64);
            const unsigned d1 = __shfl((int)pkh2[nt][2*kk+1][1], slA, 64);
            const unsigned d2 = __shfl((int)pkh2[nt][2*kk+1][0], slB, 64);
            const unsigned d3 = __shfl((int)pkh2[nt][2*kk+1][1], slB, 64);
            if (kk == 0) {
                c0.u[0] = selhi ? d0 : a0; c0.u[1] = selhi ? d1 : a1;
                c0.u[2] = selhi ? d2 : a2; c0.u[3] = selhi ? d3 : a3;
            } else {
                c1.u[0] = selhi ? d0 : a0; c1.u[1] = selhi ? d1 : a1;
                c1.u[2] = selhi ? d2 : a2; c1.u[3] = selhi ? d3 : a3;
            }
        }
        f32x4 s3 = __builtin_amdgcn_mfma_f32_16x16x32_bf16(a3f[0], c0.v, z4, 0, 0, 0);
        s3 = __builtin_amdgcn_mfma_f32_16x16x32_bf16(a3f[1], c1.v, s3, 0, 0, 0);
        if (hi < 2) {
            const int r = 32 * w + nt * 16 + lo;
#pragma unroll
            for (int e = 0; e < 4; ++e) {
                const float x  = s3[e];
                const float sp = fmaxf(x, 0.f) +
                    0.69314718f * __builtin_amdgcn_logf(
                        1.0f + __builtin_amdgcn_exp2f(-fabsf(x) * 1.44269504f));
                sca[r * 9 + hi * 4 + e] = 1.0f + sp;
            }
        }
    }

    // ====== mixed-einsum B fragments ======
    bf16x8 bfr[2][4];
#pragma unroll
    for (int n = 0; n < 2; ++n) {
        const int col = w * 32 + n * 16 + lo;
#pragma unroll
        for (int kk = 0; kk < 4; ++kk) {
            if constexpr (USE_WS) {
                bfr[n][kk] = *(const bf16x8*)(wsu + col * TD + kk * 32 + hi * 8);
            } else {
                const int k0 = kk * 32 + hi * 8;
                const float* p = mixW + (col >> 4) * 2048 + (k0 >> 4) * 256
                                      + (col & 15) * 16 + (k0 & 15);
                const float4 x = *(const float4*)p;
                const float4 y = *(const float4*)(p + 4);
                U c;
                c.u[0] = pk2(x.x, x.y); c.u[1] = pk2(x.z, x.w);
                c.u[2] = pk2(y.x, y.y); c.u[3] = pk2(y.z, y.w);
                bfr[n][kk] = c.v;
            }
        }
    }
    const float g0 = 1.f / (1.f + __builtin_amdgcn_exp2f(-gb[2 * w + 0] * 1.44269504f));
    const float g1 = 1.f / (1.f + __builtin_amdgcn_exp2f(-gb[2 * w + 1] * 1.44269504f));

    __syncthreads();   // sca complete

    // ====== phase 3: mixed einsum MFMA + fused epilogue (nontemporal stores) ======
#pragma unroll
    for (int m = 0; m < 8; ++m) {
        const int ar = m * 16 + lo;
        bf16x8 af[4];
#pragma unroll
        for (int kk = 0; kk < 4; ++kk) {
            const int slot = (kk * 4 + hi) ^ (ar & 7);
            af[kk] = *(const bf16x8*)&zs[ar * TD + slot * 8];
        }
#pragma unroll
        for (int n = 0; n < 2; ++n) {
            f32x4 acc = z4;
#pragma unroll
            for (int kk = 0; kk < 4; ++kk)
                acc = __builtin_amdgcn_mfma_f32_16x16x32_bf16(af[kk], bfr[n][kk], acc, 0, 0, 0);
            const int col = w * 32 + n * 16 + lo;
            const float gg = n ? g1 : g0;
            const int sl = col >> 3, cw = col & 7;
#pragma unroll
            for (int e = 0; e < 4; ++e) {
                const int rr = m * 16 + hi * 4 + e;
                const float zv = __uint_as_float(
                    (unsigned int)zs[rr * TD + ((sl ^ (rr & 7)) * 8) + cw] << 16);
                const float sc = sca[rr * 9 + 2 * w + n];
                __builtin_nontemporal_store(fmaf(zv, sc, gg * acc[e]),
                                            &out[(row0 + rr) * TD + col]);
            }
        }
    }
}

extern "C" void kernel_launch(void* const* d_in, const int* in_sizes, int n_in,
                              void* d_out, int out_size, void* d_ws, size_t ws_size,
                              hipStream_t stream) {
    const float* z    = (const float*)d_in[0];
    const float* W1   = (const float*)d_in[1];
    const float* b1   = (const float*)d_in[2];
    const float* W2   = (const float*)d_in[3];
    const float* b2   = (const float*)d_in[4];
    const float* W3   = (const float*)d_in[5];
    const float* mixW = (const float*)d_in[6];
    const float* gb   = (const float*)d_in[7];
    float* out = (float*)d_out;

    const int B = in_sizes[0] / TD;
    if (ws_size >= WS_NEED_BYTES && d_ws != nullptr) {
        cvt_weights<<<1, 256, 0, stream>>>(W1, W2, W3, mixW, (unsigned*)d_ws);
        soft_equiv<true><<<B / ROWS, 256, 0, stream>>>(
            z, W1, b1, W2, b2, W3, mixW, gb, (const unsigned short*)d_ws, out);
    } else {
        soft_equiv<false><<<B / ROWS, 256, 0, stream>>>(
            z, W1, b1, W2, b2, W3, mixW, gb, nullptr, out);
    }
}

// Round 16
// 111.737 us; speedup vs baseline: 3.9887x; 1.0167x over previous
//
#include <hip/hip_runtime.h>
#include <hip/hip_bf16.h>

constexpr int NB  = 8;
constexpr int TD  = 128;
constexpr int HID = 64;
constexpr int ROWS = 128;

typedef __attribute__((ext_vector_type(8))) short bf16x8;
typedef __attribute__((ext_vector_type(4))) float f32x4;

union U { unsigned u[4]; bf16x8 v; };

__device__ __forceinline__ unsigned int pk2(float a, float b) {
    __hip_bfloat162 h = __float22bfloat162_rn(float2{a, b});   // v_cvt_pk_bf16_f32 (RNE)
    unsigned int u; __builtin_memcpy(&u, &h, 4); return u;
}

// branch-free GELU: erf via Abramowitz-Stegun 7.1.26 (|err| < 1.5e-7)
__device__ __forceinline__ float gelu_fast(float x) {
    const float u = x * 0.70710678118f;
    const float a = fabsf(u);
    const float t = __builtin_amdgcn_rcpf(fmaf(0.3275911f, a, 1.0f));
    float p = fmaf(t, 1.061405429f, -1.453152027f);
    p = fmaf(t, p, 1.421413741f);
    p = fmaf(t, p, -0.284496736f);
    p = fmaf(t, p, 0.254829592f);
    p = p * t;
    const float e  = __builtin_amdgcn_exp2f(-a * a * 1.44269504f);
    const float pe = p * e;
    const float s  = (u >= 0.f) ? (2.0f - pe) : pe;   // 1 + erf(u)
    return 0.5f * x * s;
}

// ws layout (u32 pairs): [0,8192) mixW ; [8192,10240) W2 ; [10240,10496) W1 ; [10496,10752) W3
constexpr size_t WS_NEED_BYTES = 10752 * 4;

__global__ __launch_bounds__(256, 1)
void cvt_weights(const float* __restrict__ W1, const float* __restrict__ W2,
                 const float* __restrict__ W3, const float* __restrict__ mixW,
                 unsigned* __restrict__ ws)
{
    const int t = threadIdx.x;
#pragma unroll
    for (int i = 0; i < 32; ++i) {                 // mixW -> Wm[c][f], c=i*16+d, f=j*16+k
        const int p = t + i * 256;
        const int o = 2 * p;
        const int c = o >> 7, f = o & 127;
        const int ii = c >> 4, d = c & 15, j = f >> 4, k = f & 15;
        const float2 v = *(const float2*)(mixW + ii * 2048 + j * 256 + d * 16 + k);
        ws[p] = pk2(v.x, v.y);
    }
#pragma unroll
    for (int i = 0; i < 8; ++i) {                  // W2 row-major 64x64
        const int p = t + i * 256;
        const float2 v = *(const float2*)(W2 + 2 * p);
        ws[8192 + p] = pk2(v.x, v.y);
    }
    {
        const float2 v1 = *(const float2*)(W1 + 2 * t);   // W1 64x8
        ws[10240 + t] = pk2(v1.x, v1.y);
        const float2 v3 = *(const float2*)(W3 + 2 * t);   // W3 8x64
        ws[10496 + t] = pk2(v3.x, v3.y);
    }
}

template<bool USE_WS>
__global__ __launch_bounds__(256, 4)
void soft_equiv(const float* __restrict__ z,  const float* __restrict__ W1,
                const float* __restrict__ b1, const float* __restrict__ W2,
                const float* __restrict__ b2, const float* __restrict__ W3,
                const float* __restrict__ mixW, const float* __restrict__ gb,
                const unsigned short* __restrict__ wsu,
                float* __restrict__ out)
{
    __shared__ __align__(16) unsigned short zs[ROWS * TD];   // 32 KB bf16 z, swizzled
    __shared__ __align__(16) unsigned short hn[ROWS * NB];   // 2 KB bf16 norms
    __shared__ float sca[ROWS * 9];                           // 4.6 KB (1+softplus)

    const int t    = threadIdx.x;
    const int lane = t & 63;
    const int w    = t >> 6;        // wave id 0..3
    const int hi   = lane >> 4;     // 0..3
    const int lo   = lane & 15;
    const size_t row0 = (size_t)blockIdx.x * ROWS;
    const float* ztile = z + row0 * TD;
    const f32x4 z4 = {0.f, 0.f, 0.f, 0.f};

    // ====== phase 1: stage z -> bf16 swizzled LDS; in-register fp32 norms =======
#pragma unroll
    for (int i = 0; i < 4; ++i) {
        const int idx = t + i * 256;               // (row, bundle)
        const int r = idx >> 3, b = idx & 7;
        const float* p = ztile + r * TD + b * 16;
        const float4 v0 = *(const float4*)(p);
        const float4 v1 = *(const float4*)(p + 4);
        const float4 v2 = *(const float4*)(p + 8);
        const float4 v3 = *(const float4*)(p + 12);
        const int sw = r & 7;
        uint4 q0 = { pk2(v0.x, v0.y), pk2(v0.z, v0.w), pk2(v1.x, v1.y), pk2(v1.z, v1.w) };
        uint4 q1 = { pk2(v2.x, v2.y), pk2(v2.z, v2.w), pk2(v3.x, v3.y), pk2(v3.z, v3.w) };
        *(uint4*)&zs[r * TD + (((2 * b    ) ^ sw) * 8)] = q0;
        *(uint4*)&zs[r * TD + (((2 * b + 1) ^ sw) * 8)] = q1;
        float s0 = 0.f, s1 = 0.f, s2 = 0.f, s3 = 0.f;
        s0 = fmaf(v0.x, v0.x, s0); s1 = fmaf(v0.y, v0.y, s1);
        s2 = fmaf(v0.z, v0.z, s2); s3 = fmaf(v0.w, v0.w, s3);
        s0 = fmaf(v1.x, v1.x, s0); s1 = fmaf(v1.y, v1.y, s1);
        s2 = fmaf(v1.z, v1.z, s2); s3 = fmaf(v1.w, v1.w, s3);
        s0 = fmaf(v2.x, v2.x, s0); s1 = fmaf(v2.y, v2.y, s1);
        s2 = fmaf(v2.z, v2.z, s2); s3 = fmaf(v2.w, v2.w, s3);
        s0 = fmaf(v3.x, v3.x, s0); s1 = fmaf(v3.y, v3.y, s1);
        s2 = fmaf(v3.z, v3.z, s2); s3 = fmaf(v3.w, v3.w, s3);
        const float nr = sqrtf((s0 + s1) + (s2 + s3)) + 1e-8f;
        __hip_bfloat16 hb = __float2bfloat16(nr);
        unsigned short us; __builtin_memcpy(&us, &hb, 2);
        hn[r * NB + b] = us;
    }

    // ====== MLP weight fragments ======
    bf16x8 a1f[4];
    bf16x8 a2f[4][2];
    bf16x8 a3f[2];
    if constexpr (USE_WS) {
#pragma unroll
        for (int mt = 0; mt < 4; ++mt) {
            U c = {};
            if (hi == 0) c.v = *(const bf16x8*)(wsu + 2 * 10240 + (mt * 16 + lo) * 8);
            a1f[mt] = c.v;
        }
#pragma unroll
        for (int mt = 0; mt < 4; ++mt)
#pragma unroll
            for (int kk = 0; kk < 2; ++kk)
                a2f[mt][kk] = *(const bf16x8*)(wsu + 2 * 8192 + (mt * 16 + lo) * HID + kk * 32 + hi * 8);
#pragma unroll
        for (int kk = 0; kk < 2; ++kk) {
            U c = {};
            if (lo < NB) c.v = *(const bf16x8*)(wsu + 2 * 10496 + lo * HID + kk * 32 + hi * 8);
            a3f[kk] = c.v;
        }
    } else {
#pragma unroll
        for (int mt = 0; mt < 4; ++mt) {
            U c = {};
            if (hi == 0) {
                const float4 x = *(const float4*)(W1 + (mt * 16 + lo) * NB);
                const float4 y = *(const float4*)(W1 + (mt * 16 + lo) * NB + 4);
                c.u[0] = pk2(x.x, x.y); c.u[1] = pk2(x.z, x.w);
                c.u[2] = pk2(y.x, y.y); c.u[3] = pk2(y.z, y.w);
            }
            a1f[mt] = c.v;
        }
#pragma unroll
        for (int mt = 0; mt < 4; ++mt)
#pragma unroll
            for (int kk = 0; kk < 2; ++kk) {
                const float* p = W2 + (mt * 16 + lo) * HID + kk * 32 + hi * 8;
                const float4 x = *(const float4*)p;
                const float4 y = *(const float4*)(p + 4);
                U c;
                c.u[0] = pk2(x.x, x.y); c.u[1] = pk2(x.z, x.w);
                c.u[2] = pk2(y.x, y.y); c.u[3] = pk2(y.z, y.w);
                a2f[mt][kk] = c.v;
            }
#pragma unroll
        for (int kk = 0; kk < 2; ++kk) {
            U c = {};
            if (lo < NB) {
                const float* p = W3 + lo * HID + kk * 32 + hi * 8;
                const float4 x = *(const float4*)p;
                const float4 y = *(const float4*)(p + 4);
                c.u[0] = pk2(x.x, x.y); c.u[1] = pk2(x.z, x.w);
                c.u[2] = pk2(y.x, y.y); c.u[3] = pk2(y.z, y.w);
            }
            a3f[kk] = c.v;
        }
    }
    float4 b1v[4], b2v[4];
#pragma unroll
    for (int mt = 0; mt < 4; ++mt) {
        b1v[mt] = ((const float4*)b1)[mt * 4 + hi];
        b2v[mt] = ((const float4*)b2)[mt * 4 + hi];
    }

    __syncthreads();

    // ====== phase 2: MLP on MFMA (wave w owns rows 32w..32w+31) ======
    bf16x8 b1f[2];
#pragma unroll
    for (int nt = 0; nt < 2; ++nt) {
        U c = {};
        if (hi == 0)
            c.v = *(const bf16x8*)&hn[(32 * w + nt * 16 + lo) * NB];
        b1f[nt] = c.v;
    }

    const int slA = lo + 32 * (hi & 1);
    const int slB = slA + 16;
    const bool selhi = (hi & 2) != 0;

    unsigned pkh[2][4][2];
#pragma unroll
    for (int nt = 0; nt < 2; ++nt)
#pragma unroll
        for (int mt = 0; mt < 4; ++mt) {
            f32x4 c = __builtin_amdgcn_mfma_f32_16x16x32_bf16(a1f[mt], b1f[nt], z4, 0, 0, 0);
            const float4 bb = b1v[mt];
            const float g0 = gelu_fast(c[0] + bb.x);
            const float g1 = gelu_fast(c[1] + bb.y);
            const float g2 = gelu_fast(c[2] + bb.z);
            const float g3 = gelu_fast(c[3] + bb.w);
            pkh[nt][mt][0] = pk2(g0, g1);
            pkh[nt][mt][1] = pk2(g2, g3);
        }

    bf16x8 b2f[2][2];
#pragma unroll
    for (int nt = 0; nt < 2; ++nt)
#pragma unroll
        for (int kk = 0; kk < 2; ++kk) {
            U c;
            const unsigned a0 = __shfl((int)pkh[nt][2*kk  ][0], slA, 64);
            const unsigned a1 = __shfl((int)pkh[nt][2*kk  ][1], slA, 64);
            const unsigned a2 = __shfl((int)pkh[nt][2*kk  ][0], slB, 64);
            const unsigned a3 = __shfl((int)pkh[nt][2*kk  ][1], slB, 64);
            const unsigned d0 = __shfl((int)pkh[nt][2*kk+1][0], slA, 64);
            const unsigned d1 = __shfl((int)pkh[nt][2*kk+1][1], slA, 64);
            const unsigned d2 = __shfl((int)pkh[nt][2*kk+1][0], slB, 64);
            const unsigned d3 = __shfl((int)pkh[nt][2*kk+1][1], slB, 64);
            c.u[0] = selhi ? d0 : a0; c.u[1] = selhi ? d1 : a1;
            c.u[2] = selhi ? d2 : a2; c.u[3] = selhi ? d3 : a3;
            b2f[nt][kk] = c.v;
        }

    unsigned pkh2[2][4][2];
#pragma unroll
    for (int nt = 0; nt < 2; ++nt)
#pragma unroll
        for (int mt = 0; mt < 4; ++mt) {
            f32x4 c = __builtin_amdgcn_mfma_f32_16x16x32_bf16(a2f[mt][0], b2f[nt][0], z4, 0, 0, 0);
            c = __builtin_amdgcn_mfma_f32_16x16x32_bf16(a2f[mt][1], b2f[nt][1], c, 0, 0, 0);
            const float4 bb = b2v[mt];
            const float g0 = gelu_fast(c[0] + bb.x);
            const float g1 = gelu_fast(c[1] + bb.y);
            const float g2 = gelu_fast(c[2] + bb.z);
            const float g3 = gelu_fast(c[3] + bb.w);
            pkh2[nt][mt][0] = pk2(g0, g1);
            pkh2[nt][mt][1] = pk2(g2, g3);
        }

#pragma unroll
    for (int nt = 0; nt < 2; ++nt) {
        U c0, c1;
#pragma unroll
        for (int kk = 0; kk < 2; ++kk) {
            const unsigned a0 = __shfl((int)pkh2[nt][2*kk  ][0], slA, 64);
            const unsigned a1 = __shfl((int)pkh2[nt][2*kk  ][1], slA, 64);
            const unsigned a2 = __shfl((int)pkh2[nt][2*kk  ][0], slB, 64);
            const unsigned a3 = __shfl((int)pkh2[nt][2*kk  ][1], slB, 64);
            const unsigned d0 = __shfl((int)pkh2[nt][2*kk+1][0], slA, 64);
            const unsigned d1 = __shfl((int)pkh2[nt][2*kk+1][1], slA, 64);
            const unsigned d2 = __shfl((int)pkh2[nt][2*kk+1][0], slB, 64);
            const unsigned d3 = __shfl((int)pkh2[nt][2*kk+1][1], slB, 64);
            if (kk == 0) {
                c0.u[0] = selhi ? d0 : a0; c0.u[1] = selhi ? d1 : a1;
                c0.u[2] = selhi ? d2 : a2; c0.u[3] = selhi ? d3 : a3;
            } else {
                c1.u[0] = selhi ? d0 : a0; c1.u[1] = selhi ? d1 : a1;
                c1.u[2] = selhi ? d2 : a2; c1.u[3] = selhi ? d3 : a3;
            }
        }
        f32x4 s3 = __builtin_amdgcn_mfma_f32_16x16x32_bf16(a3f[0], c0.v, z4, 0, 0, 0);
        s3 = __builtin_amdgcn_mfma_f32_16x16x32_bf16(a3f[1], c1.v, s3, 0, 0, 0);
        if (hi < 2) {
            const int r = 32 * w + nt * 16 + lo;
#pragma unroll
            for (int e = 0; e < 4; ++e) {
                const float x  = s3[e];
                const float sp = fmaxf(x, 0.f) +
                    0.69314718f * __builtin_amdgcn_logf(
                        1.0f + __builtin_amdgcn_exp2f(-fabsf(x) * 1.44269504f));
                sca[r * 9 + hi * 4 + e] = 1.0f + sp;
            }
        }
    }

    // ====== mixed-einsum B fragments ======
    bf16x8 bfr[2][4];
#pragma unroll
    for (int n = 0; n < 2; ++n) {
        const int col = w * 32 + n * 16 + lo;
#pragma unroll
        for (int kk = 0; kk < 4; ++kk) {
            if constexpr (USE_WS) {
                bfr[n][kk] = *(const bf16x8*)(wsu + col * TD + kk * 32 + hi * 8);
            } else {
                const int k0 = kk * 32 + hi * 8;
                const float* p = mixW + (col >> 4) * 2048 + (k0 >> 4) * 256
                                      + (col & 15) * 16 + (k0 & 15);
                const float4 x = *(const float4*)p;
                const float4 y = *(const float4*)(p + 4);
                U c;
                c.u[0] = pk2(x.x, x.y); c.u[1] = pk2(x.z, x.w);
                c.u[2] = pk2(y.x, y.y); c.u[3] = pk2(y.z, y.w);
                bfr[n][kk] = c.v;
            }
        }
    }
    const float g0 = 1.f / (1.f + __builtin_amdgcn_exp2f(-gb[2 * w + 0] * 1.44269504f));
    const float g1 = 1.f / (1.f + __builtin_amdgcn_exp2f(-gb[2 * w + 1] * 1.44269504f));

    __syncthreads();   // sca complete

    // ====== phase 3: mixed einsum MFMA + fused epilogue ======
    // Store order: both n-halves of each 128B line issued back-to-back so the
    // nontemporal write-combiner merges them into full-line HBM writes.
#pragma unroll
    for (int m = 0; m < 8; ++m) {
        const int ar = m * 16 + lo;
        bf16x8 af[4];
#pragma unroll
        for (int kk = 0; kk < 4; ++kk) {
            const int slot = (kk * 4 + hi) ^ (ar & 7);
            af[kk] = *(const bf16x8*)&zs[ar * TD + slot * 8];
        }
        f32x4 acc0 = z4, acc1 = z4;
#pragma unroll
        for (int kk = 0; kk < 4; ++kk)
            acc0 = __builtin_amdgcn_mfma_f32_16x16x32_bf16(af[kk], bfr[0][kk], acc0, 0, 0, 0);
#pragma unroll
        for (int kk = 0; kk < 4; ++kk)
            acc1 = __builtin_amdgcn_mfma_f32_16x16x32_bf16(af[kk], bfr[1][kk], acc1, 0, 0, 0);

        const int col0 = w * 32 + lo;
        const int col1 = col0 + 16;
        const int sl0 = col0 >> 3, cw0 = col0 & 7;
        const int sl1 = col1 >> 3, cw1 = col1 & 7;
#pragma unroll
        for (int e = 0; e < 4; ++e) {
            const int rr = m * 16 + hi * 4 + e;
            const int swr = rr & 7;
            const float sc0 = sca[rr * 9 + 2 * w + 0];
            const float sc1 = sca[rr * 9 + 2 * w + 1];
            const float zv0 = __uint_as_float(
                (unsigned int)zs[rr * TD + ((sl0 ^ swr) * 8) + cw0] << 16);
            const float zv1 = __uint_as_float(
                (unsigned int)zs[rr * TD + ((sl1 ^ swr) * 8) + cw1] << 16);
            float* orow = &out[(row0 + rr) * TD];
            __builtin_nontemporal_store(fmaf(zv0, sc0, g0 * acc0[e]), orow + col0);
            __builtin_nontemporal_store(fmaf(zv1, sc1, g1 * acc1[e]), orow + col1);
        }
    }
}

extern "C" void kernel_launch(void* const* d_in, const int* in_sizes, int n_in,
                              void* d_out, int out_size, void* d_ws, size_t ws_size,
                              hipStream_t stream) {
    const float* z    = (const float*)d_in[0];
    const float* W1   = (const float*)d_in[1];
    const float* b1   = (const float*)d_in[2];
    const float* W2   = (const float*)d_in[3];
    const float* b2   = (const float*)d_in[4];
    const float* W3   = (const float*)d_in[5];
    const float* mixW = (const float*)d_in[6];
    const float* gb   = (const float*)d_in[7];
    float* out = (float*)d_out;

    const int B = in_sizes[0] / TD;
    if (ws_size >= WS_NEED_BYTES && d_ws != nullptr) {
        cvt_weights<<<1, 256, 0, stream>>>(W1, W2, W3, mixW, (unsigned*)d_ws);
        soft_equiv<true><<<B / ROWS, 256, 0, stream>>>(
            z, W1, b1, W2, b2, W3, mixW, gb, (const unsigned short*)d_ws, out);
    } else {
        soft_equiv<false><<<B / ROWS, 256, 0, stream>>>(
            z, W1, b1, W2, b2, W3, mixW, gb, nullptr, out);
    }
}

// Round 17
// 110.054 us; speedup vs baseline: 4.0497x; 1.0153x over previous
//
#include <hip/hip_runtime.h>
#include <hip/hip_bf16.h>

constexpr int NB  = 8;
constexpr int TD  = 128;
constexpr int HID = 64;
constexpr int ROWS = 128;

typedef __attribute__((ext_vector_type(8))) short bf16x8;
typedef __attribute__((ext_vector_type(4))) float f32x4;

union U { unsigned u[4]; bf16x8 v; };

__device__ __forceinline__ unsigned int pk2(float a, float b) {
    __hip_bfloat162 h = __float22bfloat162_rn(float2{a, b});   // v_cvt_pk_bf16_f32 (RNE)
    unsigned int u; __builtin_memcpy(&u, &h, 4); return u;
}

// branch-free GELU: erf via Abramowitz-Stegun 7.1.26 (|err| < 1.5e-7)
__device__ __forceinline__ float gelu_fast(float x) {
    const float u = x * 0.70710678118f;
    const float a = fabsf(u);
    const float t = __builtin_amdgcn_rcpf(fmaf(0.3275911f, a, 1.0f));
    float p = fmaf(t, 1.061405429f, -1.453152027f);
    p = fmaf(t, p, 1.421413741f);
    p = fmaf(t, p, -0.284496736f);
    p = fmaf(t, p, 0.254829592f);
    p = p * t;
    const float e  = __builtin_amdgcn_exp2f(-a * a * 1.44269504f);
    const float pe = p * e;
    const float s  = (u >= 0.f) ? (2.0f - pe) : pe;   // 1 + erf(u)
    return 0.5f * x * s;
}

// ws layout (u32 pairs): [0,8192) mixW ; [8192,10240) W2 ; [10240,10496) W1 ; [10496,10752) W3
constexpr size_t WS_NEED_BYTES = 10752 * 4;

__global__ __launch_bounds__(256, 1)
void cvt_weights(const float* __restrict__ W1, const float* __restrict__ W2,
                 const float* __restrict__ W3, const float* __restrict__ mixW,
                 unsigned* __restrict__ ws)
{
    const int t = threadIdx.x;
#pragma unroll
    for (int i = 0; i < 32; ++i) {                 // mixW -> Wm[c][f], c=i*16+d, f=j*16+k
        const int p = t + i * 256;
        const int o = 2 * p;
        const int c = o >> 7, f = o & 127;
        const int ii = c >> 4, d = c & 15, j = f >> 4, k = f & 15;
        const float2 v = *(const float2*)(mixW + ii * 2048 + j * 256 + d * 16 + k);
        ws[p] = pk2(v.x, v.y);
    }
#pragma unroll
    for (int i = 0; i < 8; ++i) {                  // W2 row-major 64x64
        const int p = t + i * 256;
        const float2 v = *(const float2*)(W2 + 2 * p);
        ws[8192 + p] = pk2(v.x, v.y);
    }
    {
        const float2 v1 = *(const float2*)(W1 + 2 * t);   // W1 64x8
        ws[10240 + t] = pk2(v1.x, v1.y);
        const float2 v3 = *(const float2*)(W3 + 2 * t);   // W3 8x64
        ws[10496 + t] = pk2(v3.x, v3.y);
    }
}

template<bool USE_WS>
__global__ __launch_bounds__(256, 4)
void soft_equiv(const float* __restrict__ z,  const float* __restrict__ W1,
                const float* __restrict__ b1, const float* __restrict__ W2,
                const float* __restrict__ b2, const float* __restrict__ W3,
                const float* __restrict__ mixW, const float* __restrict__ gb,
                const unsigned short* __restrict__ wsu,
                float* __restrict__ out)
{
    __shared__ __align__(16) unsigned short zs[ROWS * TD];   // 32 KB bf16 z, swizzled
    __shared__ __align__(16) unsigned short hn[ROWS * NB];   // 2 KB bf16 norms (wave-local)
    __shared__ float sca[ROWS * 9];                           // 4.6 KB (1+softplus)

    const int t    = threadIdx.x;
    const int lane = t & 63;
    const int w    = t >> 6;        // wave id 0..3
    const int hi   = lane >> 4;     // 0..3
    const int lo   = lane & 15;
    const size_t row0 = (size_t)blockIdx.x * ROWS;
    const float* ztile = z + row0 * TD;
    const f32x4 z4 = {0.f, 0.f, 0.f, 0.f};

    // ====== MLP weight fragments (issued first; latency overlaps staging) ======
    bf16x8 a1f[4];
    bf16x8 a2f[4][2];
    bf16x8 a3f[2];
    if constexpr (USE_WS) {
#pragma unroll
        for (int mt = 0; mt < 4; ++mt) {
            U c = {};
            if (hi == 0) c.v = *(const bf16x8*)(wsu + 2 * 10240 + (mt * 16 + lo) * 8);
            a1f[mt] = c.v;
        }
#pragma unroll
        for (int mt = 0; mt < 4; ++mt)
#pragma unroll
            for (int kk = 0; kk < 2; ++kk)
                a2f[mt][kk] = *(const bf16x8*)(wsu + 2 * 8192 + (mt * 16 + lo) * HID + kk * 32 + hi * 8);
#pragma unroll
        for (int kk = 0; kk < 2; ++kk) {
            U c = {};
            if (lo < NB) c.v = *(const bf16x8*)(wsu + 2 * 10496 + lo * HID + kk * 32 + hi * 8);
            a3f[kk] = c.v;
        }
    } else {
#pragma unroll
        for (int mt = 0; mt < 4; ++mt) {
            U c = {};
            if (hi == 0) {
                const float4 x = *(const float4*)(W1 + (mt * 16 + lo) * NB);
                const float4 y = *(const float4*)(W1 + (mt * 16 + lo) * NB + 4);
                c.u[0] = pk2(x.x, x.y); c.u[1] = pk2(x.z, x.w);
                c.u[2] = pk2(y.x, y.y); c.u[3] = pk2(y.z, y.w);
            }
            a1f[mt] = c.v;
        }
#pragma unroll
        for (int mt = 0; mt < 4; ++mt)
#pragma unroll
            for (int kk = 0; kk < 2; ++kk) {
                const float* p = W2 + (mt * 16 + lo) * HID + kk * 32 + hi * 8;
                const float4 x = *(const float4*)p;
                const float4 y = *(const float4*)(p + 4);
                U c;
                c.u[0] = pk2(x.x, x.y); c.u[1] = pk2(x.z, x.w);
                c.u[2] = pk2(y.x, y.y); c.u[3] = pk2(y.z, y.w);
                a2f[mt][kk] = c.v;
            }
#pragma unroll
        for (int kk = 0; kk < 2; ++kk) {
            U c = {};
            if (lo < NB) {
                const float* p = W3 + lo * HID + kk * 32 + hi * 8;
                const float4 x = *(const float4*)p;
                const float4 y = *(const float4*)(p + 4);
                c.u[0] = pk2(x.x, x.y); c.u[1] = pk2(x.z, x.w);
                c.u[2] = pk2(y.x, y.y); c.u[3] = pk2(y.z, y.w);
            }
            a3f[kk] = c.v;
        }
    }
    float4 b1v[4], b2v[4];
#pragma unroll
    for (int mt = 0; mt < 4; ++mt) {
        b1v[mt] = ((const float4*)b1)[mt * 4 + hi];
        b2v[mt] = ((const float4*)b2)[mt * 4 + hi];
    }

    // ====== phase 1: WAVE-LOCAL staging — wave w stages its own MLP rows ======
    // Wave w covers rows 32w..32w+31 (the exact rows its phase-2 MLP consumes),
    // so hn production->consumption is wave-local and needs NO block barrier.
#pragma unroll
    for (int i = 0; i < 4; ++i) {
        const int r = 32 * w + i * 8 + (lane >> 3);   // (row, bundle), wave-local rows
        const int b = lane & 7;
        const float* p = ztile + r * TD + b * 16;
        const float4 v0 = *(const float4*)(p);
        const float4 v1 = *(const float4*)(p + 4);
        const float4 v2 = *(const float4*)(p + 8);
        const float4 v3 = *(const float4*)(p + 12);
        const int sw = r & 7;
        uint4 q0 = { pk2(v0.x, v0.y), pk2(v0.z, v0.w), pk2(v1.x, v1.y), pk2(v1.z, v1.w) };
        uint4 q1 = { pk2(v2.x, v2.y), pk2(v2.z, v2.w), pk2(v3.x, v3.y), pk2(v3.z, v3.w) };
        *(uint4*)&zs[r * TD + (((2 * b    ) ^ sw) * 8)] = q0;
        *(uint4*)&zs[r * TD + (((2 * b + 1) ^ sw) * 8)] = q1;
        float s0 = 0.f, s1 = 0.f, s2 = 0.f, s3 = 0.f;
        s0 = fmaf(v0.x, v0.x, s0); s1 = fmaf(v0.y, v0.y, s1);
        s2 = fmaf(v0.z, v0.z, s2); s3 = fmaf(v0.w, v0.w, s3);
        s0 = fmaf(v1.x, v1.x, s0); s1 = fmaf(v1.y, v1.y, s1);
        s2 = fmaf(v1.z, v1.z, s2); s3 = fmaf(v1.w, v1.w, s3);
        s0 = fmaf(v2.x, v2.x, s0); s1 = fmaf(v2.y, v2.y, s1);
        s2 = fmaf(v2.z, v2.z, s2); s3 = fmaf(v2.w, v2.w, s3);
        s0 = fmaf(v3.x, v3.x, s0); s1 = fmaf(v3.y, v3.y, s1);
        s2 = fmaf(v3.z, v3.z, s2); s3 = fmaf(v3.w, v3.w, s3);
        const float nr = sqrtf((s0 + s1) + (s2 + s3)) + 1e-8f;
        __hip_bfloat16 hb = __float2bfloat16(nr);
        unsigned short us; __builtin_memcpy(&us, &hb, 2);
        hn[r * NB + b] = us;
    }
    // NO __syncthreads() here: phase 2 reads only wave-local hn rows.

    // ====== phase 2: MLP on MFMA (wave w owns rows 32w..32w+31) ======
    bf16x8 b1f[2];
#pragma unroll
    for (int nt = 0; nt < 2; ++nt) {
        U c = {};
        if (hi == 0)
            c.v = *(const bf16x8*)&hn[(32 * w + nt * 16 + lo) * NB];
        b1f[nt] = c.v;
    }

    const int slA = lo + 32 * (hi & 1);
    const int slB = slA + 16;
    const bool selhi = (hi & 2) != 0;

    unsigned pkh[2][4][2];
#pragma unroll
    for (int nt = 0; nt < 2; ++nt)
#pragma unroll
        for (int mt = 0; mt < 4; ++mt) {
            f32x4 c = __builtin_amdgcn_mfma_f32_16x16x32_bf16(a1f[mt], b1f[nt], z4, 0, 0, 0);
            const float4 bb = b1v[mt];
            const float g0 = gelu_fast(c[0] + bb.x);
            const float g1 = gelu_fast(c[1] + bb.y);
            const float g2 = gelu_fast(c[2] + bb.z);
            const float g3 = gelu_fast(c[3] + bb.w);
            pkh[nt][mt][0] = pk2(g0, g1);
            pkh[nt][mt][1] = pk2(g2, g3);
        }

    bf16x8 b2f[2][2];
#pragma unroll
    for (int nt = 0; nt < 2; ++nt)
#pragma unroll
        for (int kk = 0; kk < 2; ++kk) {
            U c;
            const unsigned a0 = __shfl((int)pkh[nt][2*kk  ][0], slA, 64);
            const unsigned a1 = __shfl((int)pkh[nt][2*kk  ][1], slA, 64);
            const unsigned a2 = __shfl((int)pkh[nt][2*kk  ][0], slB, 64);
            const unsigned a3 = __shfl((int)pkh[nt][2*kk  ][1], slB, 64);
            const unsigned d0 = __shfl((int)pkh[nt][2*kk+1][0], slA, 64);
            const unsigned d1 = __shfl((int)pkh[nt][2*kk+1][1], slA, 64);
            const unsigned d2 = __shfl((int)pkh[nt][2*kk+1][0], slB, 64);
            const unsigned d3 = __shfl((int)pkh[nt][2*kk+1][1], slB, 64);
            c.u[0] = selhi ? d0 : a0; c.u[1] = selhi ? d1 : a1;
            c.u[2] = selhi ? d2 : a2; c.u[3] = selhi ? d3 : a3;
            b2f[nt][kk] = c.v;
        }

    unsigned pkh2[2][4][2];
#pragma unroll
    for (int nt = 0; nt < 2; ++nt)
#pragma unroll
        for (int mt = 0; mt < 4; ++mt) {
            f32x4 c = __builtin_amdgcn_mfma_f32_16x16x32_bf16(a2f[mt][0], b2f[nt][0], z4, 0, 0, 0);
            c = __builtin_amdgcn_mfma_f32_16x16x32_bf16(a2f[mt][1], b2f[nt][1], c, 0, 0, 0);
            const float4 bb = b2v[mt];
            const float g0 = gelu_fast(c[0] + bb.x);
            const float g1 = gelu_fast(c[1] + bb.y);
            const float g2 = gelu_fast(c[2] + bb.z);
            const float g3 = gelu_fast(c[3] + bb.w);
            pkh2[nt][mt][0] = pk2(g0, g1);
            pkh2[nt][mt][1] = pk2(g2, g3);
        }

#pragma unroll
    for (int nt = 0; nt < 2; ++nt) {
        U c0, c1;
#pragma unroll
        for (int kk = 0; kk < 2; ++kk) {
            const unsigned a0 = __shfl((int)pkh2[nt][2*kk  ][0], slA, 64);
            const unsigned a1 = __shfl((int)pkh2[nt][2*kk  ][1], slA, 64);
            const unsigned a2 = __shfl((int)pkh2[nt][2*kk  ][0], slB, 64);
            const unsigned a3 = __shfl((int)pkh2[nt][2*kk  ][1], slB, 64);
            const unsigned d0 = __shfl((int)pkh2[nt][2*kk+1][0], slA, 64);
            const unsigned d1 = __shfl((int)pkh2[nt][2*kk+1][1], slA, 64);
            const unsigned d2 = __shfl((int)pkh2[nt][2*kk+1][0], slB, 64);
            const unsigned d3 = __shfl((int)pkh2[nt][2*kk+1][1], slB, 64);
            if (kk == 0) {
                c0.u[0] = selhi ? d0 : a0; c0.u[1] = selhi ? d1 : a1;
                c0.u[2] = selhi ? d2 : a2; c0.u[3] = selhi ? d3 : a3;
            } else {
                c1.u[0] = selhi ? d0 : a0; c1.u[1] = selhi ? d1 : a1;
                c1.u[2] = selhi ? d2 : a2; c1.u[3] = selhi ? d3 : a3;
            }
        }
        f32x4 s3 = __builtin_amdgcn_mfma_f32_16x16x32_bf16(a3f[0], c0.v, z4, 0, 0, 0);
        s3 = __builtin_amdgcn_mfma_f32_16x16x32_bf16(a3f[1], c1.v, s3, 0, 0, 0);
        if (hi < 2) {
            const int r = 32 * w + nt * 16 + lo;
#pragma unroll
            for (int e = 0; e < 4; ++e) {
                const float x  = s3[e];
                const float sp = fmaxf(x, 0.f) +
                    0.69314718f * __builtin_amdgcn_logf(
                        1.0f + __builtin_amdgcn_exp2f(-fabsf(x) * 1.44269504f));
                sca[r * 9 + hi * 4 + e] = 1.0f + sp;
            }
        }
    }

    // ====== mixed-einsum B fragments ======
    bf16x8 bfr[2][4];
#pragma unroll
    for (int n = 0; n < 2; ++n) {
        const int col = w * 32 + n * 16 + lo;
#pragma unroll
        for (int kk = 0; kk < 4; ++kk) {
            if constexpr (USE_WS) {
                bfr[n][kk] = *(const bf16x8*)(wsu + col * TD + kk * 32 + hi * 8);
            } else {
                const int k0 = kk * 32 + hi * 8;
                const float* p = mixW + (col >> 4) * 2048 + (k0 >> 4) * 256
                                      + (col & 15) * 16 + (k0 & 15);
                const float4 x = *(const float4*)p;
                const float4 y = *(const float4*)(p + 4);
                U c;
                c.u[0] = pk2(x.x, x.y); c.u[1] = pk2(x.z, x.w);
                c.u[2] = pk2(y.x, y.y); c.u[3] = pk2(y.z, y.w);
                bfr[n][kk] = c.v;
            }
        }
    }
    const float g0 = 1.f / (1.f + __builtin_amdgcn_exp2f(-gb[2 * w + 0] * 1.44269504f));
    const float g1 = 1.f / (1.f + __builtin_amdgcn_exp2f(-gb[2 * w + 1] * 1.44269504f));

    __syncthreads();   // zs (all waves) + sca complete

    // ====== phase 3: mixed einsum MFMA + fused epilogue ======
    // Both n-halves of each 128B line stored back-to-back -> full-line NT writes.
#pragma unroll
    for (int m = 0; m < 8; ++m) {
        const int ar = m * 16 + lo;
        bf16x8 af[4];
#pragma unroll
        for (int kk = 0; kk < 4; ++kk) {
            const int slot = (kk * 4 + hi) ^ (ar & 7);
            af[kk] = *(const bf16x8*)&zs[ar * TD + slot * 8];
        }
        f32x4 acc0 = z4, acc1 = z4;
#pragma unroll
        for (int kk = 0; kk < 4; ++kk)
            acc0 = __builtin_amdgcn_mfma_f32_16x16x32_bf16(af[kk], bfr[0][kk], acc0, 0, 0, 0);
#pragma unroll
        for (int kk = 0; kk < 4; ++kk)
            acc1 = __builtin_amdgcn_mfma_f32_16x16x32_bf16(af[kk], bfr[1][kk], acc1, 0, 0, 0);

        const int col0 = w * 32 + lo;
        const int col1 = col0 + 16;
        const int sl0 = col0 >> 3, cw0 = col0 & 7;
        const int sl1 = col1 >> 3, cw1 = col1 & 7;
#pragma unroll
        for (int e = 0; e < 4; ++e) {
            const int rr = m * 16 + hi * 4 + e;
            const int swr = rr & 7;
            const float sc0 = sca[rr * 9 + 2 * w + 0];
            const float sc1 = sca[rr * 9 + 2 * w + 1];
            const float zv0 = __uint_as_float(
                (unsigned int)zs[rr * TD + ((sl0 ^ swr) * 8) + cw0] << 16);
            const float zv1 = __uint_as_float(
                (unsigned int)zs[rr * TD + ((sl1 ^ swr) * 8) + cw1] << 16);
            float* orow = &out[(row0 + rr) * TD];
            __builtin_nontemporal_store(fmaf(zv0, sc0, g0 * acc0[e]), orow + col0);
            __builtin_nontemporal_store(fmaf(zv1, sc1, g1 * acc1[e]), orow + col1);
        }
    }
}

extern "C" void kernel_launch(void* const* d_in, const int* in_sizes, int n_in,
                              void* d_out, int out_size, void* d_ws, size_t ws_size,
                              hipStream_t stream) {
    const float* z    = (const float*)d_in[0];
    const float* W1   = (const float*)d_in[1];
    const float* b1   = (const float*)d_in[2];
    const float* W2   = (const float*)d_in[3];
    const float* b2   = (const float*)d_in[4];
    const float* W3   = (const float*)d_in[5];
    const float* mixW = (const float*)d_in[6];
    const float* gb   = (const float*)d_in[7];
    float* out = (float*)d_out;

    const int B = in_sizes[0] / TD;
    if (ws_size >= WS_NEED_BYTES && d_ws != nullptr) {
        cvt_weights<<<1, 256, 0, stream>>>(W1, W2, W3, mixW, (unsigned*)d_ws);
        soft_equiv<true><<<B / ROWS, 256, 0, stream>>>(
            z, W1, b1, W2, b2, W3, mixW, gb, (const unsigned short*)d_ws, out);
    } else {
        soft_equiv<false><<<B / ROWS, 256, 0, stream>>>(
            z, W1, b1, W2, b2, W3, mixW, gb, nullptr, out);
    }
}